// Round 3
// baseline (148.736 us; speedup 1.0000x reference)
//
#include <hip/hip_runtime.h>
#include <hip/hip_bf16.h>
#include <hip/hip_fp16.h>
#include <cstdint>
#include <random>

typedef __attribute__((ext_vector_type(8))) short short8;   // 8 bf16 = 4 VGPRs
typedef __attribute__((ext_vector_type(4))) float floatx4;  // MFMA C/D

// ---------------------------------------------------------------------------
// Gate spec replication of numpy RandomState(12345) sequence (host side).
// randint(n), n small: ONE 32-bit MT draw per attempt, masked rejection.
// choice(4,2,False) = permutation(4)[:2], Fisher-Yates i=3,2,1, 32-bit draws.
// type: 0=rx 1=ry 2=rz 3=crx 4=cnot 5=H 6=SX ; src: 0=rand_params 1=gate_params 2=none
// ---------------------------------------------------------------------------
#define NGMAX 60
struct GateSpec {
  unsigned char type[NGMAX];
  unsigned char w0[NGMAX];
  unsigned char w1[NGMAX];
  signed char   src[NGMAX];
  signed char   pidx[NGMAX];
  int n;
};

static GateSpec build_spec() {
  GateSpec sp; sp.n = 0;
  std::mt19937 mt(12345u);
  int p = 0;
  auto add = [&](int ty, int a, int b, int s, int pi) {
    sp.type[sp.n] = (unsigned char)ty; sp.w0[sp.n] = (unsigned char)a;
    sp.w1[sp.n] = (unsigned char)b; sp.src[sp.n] = (signed char)s;
    sp.pidx[sp.n] = (signed char)pi; sp.n++;
  };
  for (int op = 0; op < 50; ++op) {
    unsigned g;
    for (;;) { uint32_t v = mt() & 7u; if (v <= 4u) { g = v; break; } }
    if (g == 3u || g == 4u) {
      int arr[4] = {0, 1, 2, 3};
      for (int i = 3; i >= 1; --i) {
        uint32_t mask = (i == 1) ? 1u : 3u;
        uint32_t j;
        for (;;) { j = mt() & mask; if (j <= (uint32_t)i) break; }
        int t = arr[i]; arr[i] = arr[j]; arr[j] = t;
      }
      if (g == 3u) add(3, arr[0], arr[1], 0, p++);
      else         add(4, arr[0], arr[1], 2, -1);
    } else {
      int w = (int)(mt() & 3u);
      add((int)g, w, 0, 0, p++);
    }
  }
  add(0, 0, 0, 1, 0);
  add(1, 1, 0, 1, 1);
  add(2, 3, 0, 1, 2);
  add(3, 0, 2, 1, 3);
  add(5, 3, 0, 2, -1);
  add(6, 2, 0, 2, -1);
  add(4, 3, 0, 2, -1);
  return sp;
}

__device__ __forceinline__ float2 cmul(float2 a, float2 b) {
  return make_float2(fmaf(a.x, b.x, -a.y * b.y), fmaf(a.x, b.y, a.y * b.x));
}

__device__ __forceinline__ unsigned short f2bf(float f) {
  __hip_bfloat16 h = __float2bfloat16(f);
  return *reinterpret_cast<unsigned short*>(&h);
}

// ---------------------------------------------------------------------------
// Workspace layout (FLOAT offsets, with correct byte sizes!):
//   U    [0,    512)  : 16x16 complex fp32           (2048 B)
//   Bw   [512, 1408)  : 16x112 bf16 = 3584 B = 896 floats
//   w1c  [1408,1456)  : 4x12 half2 = 192 B = 48 floats
//   o4   [1456, ...)  : B*4 fp32
// ---------------------------------------------------------------------------
#define WS_BW   512
#define WS_W1C  1408
#define WS_O4   1456

// ---------------------------------------------------------------------------
// Prep kernel (1 block, 256 threads): batch-invariant 16x16 unitary +
// pre-transposed weights into workspace. (unchanged, validated)
// ---------------------------------------------------------------------------
__global__ void prep_kernel(const float* __restrict__ rp, const float* __restrict__ gp,
                            const float* __restrict__ c1w, const float* __restrict__ c1b,
                            const float* __restrict__ c2w,
                            float* __restrict__ ws, GateSpec sp) {
  const int tid = threadIdx.x;

  __hip_bfloat16* Bwg = (__hip_bfloat16*)(ws + WS_BW);   // [co][k], k padded 72->112
  __half2* w1cg = (__half2*)(ws + WS_W1C);               // [p][12]: taps 0..8, [9]=bias
  for (int i = tid; i < 896; i += 256)
    ((unsigned int*)Bwg)[i] = 0u;
  __syncthreads();
  for (int i = tid; i < 1152; i += 256) {                // [co][ci][tap] -> Bw[co][tap*8+ci]
    const int co = i / 72, rem = i - co * 72;
    const int ci = rem / 9, tap = rem - ci * 9;
    Bwg[co * 112 + tap * 8 + ci] = __float2bfloat16(c2w[i]);
  }
  if (tid < 40) {                                        // conv1 [p][12] packed f16
    const int p = tid / 10, t = tid - p * 10;
    __half2 v;
    if (t < 9) v = __halves2half2(__float2half(c1w[(2 * p) * 9 + t]),
                                  __float2half(c1w[(2 * p + 1) * 9 + t]));
    else       v = __halves2half2(__float2half(c1b[2 * p]), __float2half(c1b[2 * p + 1]));
    w1cg[p * 12 + t] = v;
  }

  const int r = tid & 15;   // row
  const int c = tid >> 4;   // col
  float2 u = make_float2((r == c) ? 1.f : 0.f, 0.f);
  for (int g = 0; g < sp.n; ++g) {
    const int ty = sp.type[g];
    float th = 0.f;
    const int s = sp.src[g];
    if (s == 0) th = rp[(int)sp.pidx[g]];
    else if (s == 1) th = gp[(int)sp.pidx[g]];
    const float ch = cosf(th * 0.5f), sh = sinf(th * 0.5f);
    if (ty == 0) {              // rx
      const int m = 1 << (3 - sp.w0[g]);
      const float px_ = __shfl_xor(u.x, m), py_ = __shfl_xor(u.y, m);
      u = make_float2(fmaf(ch, u.x, sh * py_), fmaf(ch, u.y, -sh * px_));
    } else if (ty == 1) {       // ry
      const int bp = 3 - sp.w0[g]; const int m = 1 << bp; const int b = (r >> bp) & 1;
      const float px_ = __shfl_xor(u.x, m), py_ = __shfl_xor(u.y, m);
      const float sgn = b ? sh : -sh;
      u = make_float2(fmaf(ch, u.x, sgn * px_), fmaf(ch, u.y, sgn * py_));
    } else if (ty == 2) {       // rz
      const int bp = 3 - sp.w0[g]; const int b = (r >> bp) & 1;
      u = cmul(make_float2(ch, b ? sh : -sh), u);
    } else if (ty == 3) {       // crx
      const int bpc = 3 - sp.w0[g]; const int m = 1 << (3 - sp.w1[g]);
      const float px_ = __shfl_xor(u.x, m), py_ = __shfl_xor(u.y, m);
      if ((r >> bpc) & 1)
        u = make_float2(fmaf(ch, u.x, sh * py_), fmaf(ch, u.y, -sh * px_));
    } else if (ty == 4) {       // cnot
      const int bpc = 3 - sp.w0[g]; const int m = 1 << (3 - sp.w1[g]);
      const float px_ = __shfl_xor(u.x, m), py_ = __shfl_xor(u.y, m);
      if ((r >> bpc) & 1) u = make_float2(px_, py_);
    } else if (ty == 5) {       // H
      const int bp = 3 - sp.w0[g]; const int m = 1 << bp; const int b = (r >> bp) & 1;
      const float px_ = __shfl_xor(u.x, m), py_ = __shfl_xor(u.y, m);
      const float is2 = 0.70710678118654752f;
      u = b ? make_float2(is2 * (px_ - u.x), is2 * (py_ - u.y))
            : make_float2(is2 * (u.x + px_), is2 * (u.y + py_));
    } else {                    // SX
      const int m = 1 << (3 - sp.w0[g]);
      const float px_ = __shfl_xor(u.x, m), py_ = __shfl_xor(u.y, m);
      u = make_float2(0.5f * (u.x - u.y + px_ + py_), 0.5f * (u.x + u.y + py_ - px_));
    }
  }
  ws[2 * (r * 16 + c) + 0] = u.x;
  ws[2 * (r * 16 + c) + 1] = u.y;
}

// ---------------------------------------------------------------------------
// Main kernel: ONE WAVE PER IMAGE, 4 images per 256-thread block.
// All data dependencies are intra-wave (wave-private LDS slices; conv2 MFMA
// is per-wave by definition; quantum tail entirely in registers via shfl).
// Barriers: 9 -> 2. pooled[] LDS eliminated (mean fused into conv2 epilogue).
// LDS/block: sxp2 4*3600B + h1t 4*4864B = 33856 B -> 4 blocks/CU.
// ---------------------------------------------------------------------------
__global__ __launch_bounds__(256, 4) void cnn_quantum_kernel(
    const float* __restrict__ x,
    const float* __restrict__ c2b,
    const float* __restrict__ ws,
    float* __restrict__ o4, int B) {
  __shared__ __align__(16) __half2 sxp2[4 * 900];           // per-wave 30x30 f16 pairs
  __shared__ __align__(16) unsigned short h1t[4 * 304 * 8]; // per-wave bf16 [site][ci]

  const int tid  = threadIdx.x;
  const int lane = tid & 63;
  const int wid  = tid >> 6;
  int img = blockIdx.x * 4 + wid;
  if (img >= B) img = B - 1;          // clamp: duplicate compute, benign dup store

  const float* __restrict__ Ug = ws;                           // 16x16 complex
  const __hip_bfloat16* __restrict__ Bwg = (const __hip_bfloat16*)(ws + WS_BW);
  const __half2* __restrict__ w1cg = (const __half2*)(ws + WS_W1C);

  __half2* swave = sxp2 + wid * 900;
  unsigned short* hwave = h1t + wid * 304 * 8;

  // ---- phase A: zero fills + stage input (per wave) ----
  for (int i = lane; i < 116; i += 64) {               // sxp2 border (30+30+56)
    int idx;
    if (i < 30) idx = i;
    else if (i < 60) idx = 870 + (i - 30);
    else { const int r = (i - 60) >> 1, c = (i - 60) & 1; idx = (r + 1) * 30 + (c ? 29 : 0); }
    swave[idx] = __float2half2_rn(0.f);
  }
  {                                                    // h1t: ALL 304 rows, b128 each
    const uint4 z4 = make_uint4(0u, 0u, 0u, 0u);
    uint4* h4 = (uint4*)hwave;
    for (int s = lane; s < 304; s += 64) h4[s] = z4;
  }
  const float* xb = x + (size_t)img * 784;
  for (int t = lane; t < 196; t += 64) {
    const float4 v4 = *(const float4*)(xb + 4 * t);
    const int yy = t / 7;                              // 4*t/28
    const int xoff = 4 * (t - 7 * yy);
    __half2* dst = &swave[(yy + 1) * 30 + xoff + 1];
    dst[0] = __float2half2_rn(v4.x);
    dst[1] = __float2half2_rn(v4.y);
    dst[2] = __float2half2_rn(v4.z);
    dst[3] = __float2half2_rn(v4.w);
  }
  __syncthreads();   // fence 1 (cross-lane LDS visibility, waves balanced)

  // ---- conv1 (1->8, 3x3 SAME) + bias + relu + 2x2 maxpool, per wave ----
  {
    const int p = lane & 3;       // channel pair (2p, 2p+1)
    const int grp = lane >> 2;    // 0..15 site groups
    const __half2* __restrict__ wrow = w1cg + p * 12;
    __half2 wr[9];
#pragma unroll
    for (int k = 0; k < 9; ++k) wr[k] = wrow[k];
    const __half2 bias = wrow[9];
    for (int s = grp; s < 196; s += 16) {
      const int py = s / 14, px = s - py * 14;
      const int base = 2 * (py * 30 + px);             // even -> b64 merges
      __half2 q[4][4];
#pragma unroll
      for (int j = 0; j < 4; ++j) {
        const __half2* rowp = &swave[base + j * 30];
        q[j][0] = rowp[0]; q[j][1] = rowp[1]; q[j][2] = rowp[2]; q[j][3] = rowp[3];
      }
      __half2 s00 = bias, s01 = bias, s10 = bias, s11 = bias;
#pragma unroll
      for (int ky = 0; ky < 3; ++ky)
#pragma unroll
        for (int kx = 0; kx < 3; ++kx) {
          const __half2 w = wr[ky * 3 + kx];
          s00 = __hfma2(q[ky][kx], w, s00);
          s01 = __hfma2(q[ky][kx + 1], w, s01);
          s10 = __hfma2(q[ky + 1][kx], w, s10);
          s11 = __hfma2(q[ky + 1][kx + 1], w, s11);
        }
      const float lo = fmaxf(fmaxf(fmaxf(__low2float(s00), __low2float(s01)),
                                   fmaxf(__low2float(s10), __low2float(s11))), 0.f);
      const float hi = fmaxf(fmaxf(fmaxf(__high2float(s00), __high2float(s01)),
                                   fmaxf(__high2float(s10), __high2float(s11))), 0.f);
      const int site = (py + 1) * 16 + (px + 1);
      const unsigned int pk = (unsigned int)f2bf(lo) | ((unsigned int)f2bf(hi) << 16);
      *(unsigned int*)&hwave[site * 8 + 2 * p] = pk;   // one 4B LDS store
    }
  }
  __syncthreads();   // fence 2

  // ---- conv2 via per-wave MFMA (13 tiles), mean fused into epilogue ----
  float asum = 0.f;
  {
    const int n = lane & 15;        // co
    const int g = lane >> 4;        // k-group / row-group

    short8 bfrag[3];
#pragma unroll
    for (int kt = 0; kt < 3; ++kt)
      bfrag[kt] = *(const short8*)&Bwg[n * 112 + kt * 32 + g * 8];
    const float bias2 = c2b[n];

    for (int t = 0; t < 13; ++t) {
      const int m = lane & 15;
      const int S = t * 16 + m;
      const int p = S >> 2, q = S & 3;
      const int p7 = p / 7;
      const int py = 2 * p7 + (q >> 1);
      const int px = 2 * (p - 7 * p7) + (q & 1);
      floatx4 acc = {0.f, 0.f, 0.f, 0.f};
#pragma unroll
      for (int kt = 0; kt < 3; ++kt) {
        const int tap = kt * 4 + g;               // taps 9..11 hit zero rows
        const int dy = tap / 3, dx = tap - 3 * dy;
        const short8 a = *(const short8*)&hwave[((py + dy) * 16 + (px + dx)) * 8];
        acc = __builtin_amdgcn_mfma_f32_16x16x32_bf16(a, bfrag[kt], acc, 0, 0, 0);
      }
      const int pq = t * 4 + g;                   // lane rows 4g..4g+3 = quad pq
      if (pq < 49) {
        const float v = fmaxf(fmaxf(acc[0], acc[1]), fmaxf(acc[2], acc[3]));
        asum += fmaxf(v + bias2, 0.f);
      }
    }
    // reduce over the 4 g-groups: every lane ends with total for n = lane&15
    asum += __shfl_xor(asum, 16);
    asum += __shfl_xor(asum, 32);
  }

  // ---- quantum tail: registers + shfl only, zero barriers ----
  const float angw = asum * (1.0f / 49.0f);       // lane holds ang[lane&15]

  // encoder: per-wire v_w = ry(a3) rx(a2) rz(a1) ry(a0) |0>  (wire = lane&3)
  const int w = lane & 3;
  const float a0 = __shfl(angw, w);
  const float a1 = __shfl(angw, 4 + w);
  const float a2 = __shfl(angw, 8 + w);
  const float a3 = __shfl(angw, 12 + w);
  float c0, s0; sincosf(a0 * 0.5f, &s0, &c0);
  float2 v0 = make_float2(c0, 0.f), v1 = make_float2(s0, 0.f);
  float c1, s1; sincosf(a1 * 0.5f, &s1, &c1);
  v0 = cmul(make_float2(c1, -s1), v0);
  v1 = cmul(make_float2(c1, s1), v1);
  float c2, s2; sincosf(a2 * 0.5f, &s2, &c2);
  const float2 iv0 = make_float2(-v0.y, v0.x);
  const float2 iv1 = make_float2(-v1.y, v1.x);
  const float2 nv0 = make_float2(c2 * v0.x - s2 * iv1.x, c2 * v0.y - s2 * iv1.y);
  const float2 nv1 = make_float2(c2 * v1.x - s2 * iv0.x, c2 * v1.y - s2 * iv0.y);
  float c3, s3; sincosf(a3 * 0.5f, &s3, &c3);
  v0 = make_float2(c3 * nv0.x - s3 * nv1.x, c3 * nv0.y - s3 * nv1.y);
  v1 = make_float2(s3 * nv0.x + c3 * nv1.x, s3 * nv0.y + c3 * nv1.y);

  // product state (wire0 = MSB): basis index t = lane&15
  const int t16 = lane & 15;
  float2 psi = make_float2(1.f, 0.f);
#pragma unroll
  for (int ww = 0; ww < 4; ++ww) {
    const float g0x = __shfl(v0.x, ww), g0y = __shfl(v0.y, ww);
    const float g1x = __shfl(v1.x, ww), g1y = __shfl(v1.y, ww);
    const int bb = (t16 >> (3 - ww)) & 1;
    const float2 vw = bb ? make_float2(g1x, g1y) : make_float2(g0x, g0y);
    psi = cmul(psi, vw);
  }

  // phi = U psi, prob = |phi|^2  (row t16 per lane; U rows L1-cached)
  const float2* __restrict__ Uc = (const float2*)Ug;
  float2 accp = make_float2(0.f, 0.f);
#pragma unroll
  for (int j = 0; j < 16; ++j) {
    const float2 uu = Uc[t16 * 16 + j];
    const float ppx = __shfl(psi.x, j), ppy = __shfl(psi.y, j);
    accp.x = fmaf(uu.x, ppx, accp.x); accp.x = fmaf(-uu.y, ppy, accp.x);
    accp.y = fmaf(uu.x, ppy, accp.y); accp.y = fmaf(uu.y, ppx, accp.y);
  }
  const float pr = accp.x * accp.x + accp.y * accp.y;

  // Z expectations: per-lane signed 4-vector, butterfly over 16-lane group
  float e0 = (t16 & 8) ? -pr : pr;
  float e1 = (t16 & 4) ? -pr : pr;
  float e2 = (t16 & 2) ? -pr : pr;
  float e3 = (t16 & 1) ? -pr : pr;
#pragma unroll
  for (int m = 1; m <= 8; m <<= 1) {
    e0 += __shfl_xor(e0, m); e1 += __shfl_xor(e1, m);
    e2 += __shfl_xor(e2, m); e3 += __shfl_xor(e3, m);
  }
  if (lane == 0) {
    float4 r; r.x = e0; r.y = e1; r.z = e2; r.w = e3;
    *(float4*)(o4 + (size_t)img * 4) = r;      // 16B aligned
  }
}

// ---------------------------------------------------------------------------
// Finalize: BatchNorm (batch stats) + Linear 4->1. (unchanged, validated)
// ---------------------------------------------------------------------------
__global__ __launch_bounds__(1024) void bn_fc_kernel(
    const float* __restrict__ o4, const float* __restrict__ gamma,
    const float* __restrict__ beta, const float* __restrict__ fcw,
    const float* __restrict__ fcb, float* __restrict__ out, int B) {
  __shared__ float redS[16][8];
  __shared__ float coef[5];
  const int tid = threadIdx.x;
  float s0 = 0, s1 = 0, s2 = 0, s3 = 0, q0 = 0, q1 = 0, q2 = 0, q3 = 0;
  for (int r = tid; r < B; r += 1024) {
    const float4 v = *(const float4*)(o4 + (size_t)r * 4);
    s0 += v.x; s1 += v.y; s2 += v.z; s3 += v.w;
    q0 += v.x * v.x; q1 += v.y * v.y; q2 += v.z * v.z; q3 += v.w * v.w;
  }
#pragma unroll
  for (int off = 32; off > 0; off >>= 1) {
    s0 += __shfl_down(s0, off); s1 += __shfl_down(s1, off);
    s2 += __shfl_down(s2, off); s3 += __shfl_down(s3, off);
    q0 += __shfl_down(q0, off); q1 += __shfl_down(q1, off);
    q2 += __shfl_down(q2, off); q3 += __shfl_down(q3, off);
  }
  const int wv = tid >> 6, ln = tid & 63;
  if (ln == 0) {
    redS[wv][0] = s0; redS[wv][1] = s1; redS[wv][2] = s2; redS[wv][3] = s3;
    redS[wv][4] = q0; redS[wv][5] = q1; redS[wv][6] = q2; redS[wv][7] = q3;
  }
  __syncthreads();
  if (tid == 0) {
    float S[8] = {0, 0, 0, 0, 0, 0, 0, 0};
    for (int w = 0; w < 16; ++w)
      for (int k = 0; k < 8; ++k) S[k] += redS[w][k];
    float C = fcb[0];
    for (int k = 0; k < 4; ++k) {
      const float mu = S[k] / (float)B;
      const float var = S[4 + k] / (float)B - mu * mu;
      const float rstd = 1.0f / sqrtf(var + 1e-5f);
      coef[k] = fcw[k] * gamma[k] * rstd;
      C += fcw[k] * (beta[k] - mu * rstd * gamma[k]);
    }
    coef[4] = C;
  }
  __syncthreads();
  const float A0 = coef[0], A1 = coef[1], A2 = coef[2], A3 = coef[3], Cc = coef[4];
  const int r = blockIdx.x * 256 + tid;
  if (tid < 256 && r < B) {
    const float4 v = *(const float4*)(o4 + (size_t)r * 4);
    out[r] = Cc + A0 * v.x + A1 * v.y + A2 * v.z + A3 * v.w;
  }
}

// ---------------------------------------------------------------------------
extern "C" void kernel_launch(void* const* d_in, const int* in_sizes, int n_in,
                              void* d_out, int out_size, void* d_ws, size_t ws_size,
                              hipStream_t stream) {
  const float* x   = (const float*)d_in[0];
  const float* c1w = (const float*)d_in[1];
  const float* c1b = (const float*)d_in[2];
  const float* c2w = (const float*)d_in[3];
  const float* c2b = (const float*)d_in[4];
  const float* gp  = (const float*)d_in[5];   // gate_params
  const float* rp  = (const float*)d_in[6];   // rand_params
  const float* gam = (const float*)d_in[7];
  const float* bet = (const float*)d_in[8];
  const float* fcw = (const float*)d_in[9];
  const float* fcb = (const float*)d_in[10];
  float* out = (float*)d_out;
  const int B = in_sizes[0] / 784;

  float* ws = (float*)d_ws;
  float* o4 = ws + WS_O4;

  GateSpec sp = build_spec();
  prep_kernel<<<1, 256, 0, stream>>>(rp, gp, c1w, c1b, c2w, ws, sp);
  const int nblk = (B + 3) / 4;
  cnn_quantum_kernel<<<nblk, 256, 0, stream>>>(x, c2b, ws, o4, B);
  const int nfin = (B + 255) / 256;
  bn_fc_kernel<<<nfin, 1024, 0, stream>>>(o4, gam, bet, fcw, fcb, out, B);
}